// Round 2
// baseline (84.167 us; speedup 1.0000x reference)
//
#include <hip/hip_runtime.h>
#include <hip/hip_bf16.h>

#define BB 8
#define SS 128
#define DD 480
#define EE 8
#define CC 10
#define KK 10
#define FF 994

__device__ __forceinline__ float cvt(float x) { return x; }
__device__ __forceinline__ float cvt(__hip_bfloat16 x) { return __bfloat162float(x); }
__device__ __forceinline__ void stf(float* p, float v) { *p = v; }
__device__ __forceinline__ void stf(__hip_bfloat16* p, float v) { *p = __float2bfloat16(v); }

// Dtype probe: weight_prob is uniform [0,1). If the buffer really holds bf16,
// every u16 has exponent field < 127. If it holds fp32, the low-half u16 of
// each float is random mantissa bits -> bf16-exponent >= 128 with p~0.25 each.
// 256 u16s examined -> P(misdetect fp32 as bf16) ~ 0.75^128 ~ 1e-16.
__global__ __launch_bounds__(64) void detect_kernel(const unsigned short* __restrict__ wp_raw,
                                                    int* __restrict__ flag) {
    int bad = 0;
    #pragma unroll
    for (int q = 0; q < 4; ++q) {
        unsigned short v = wp_raw[threadIdx.x + 64 * q];
        if (((v >> 7) & 0xFF) >= 128) bad = 1;
    }
    unsigned long long m = __ballot(bad);
    if (threadIdx.x == 0) *flag = (m != 0ULL) ? 1 : 0;
}

// Row terms:
//   Arow[b,s,k] = gcn[b,s]·W[k,0:480]   + wp[b,s,s,:]·W[k,960:968]
//   Brow[b,s,k] = gcn[b,s]·W[k,480:960] + wp[b,s,s,:]·W[k,968:976] + bias[k]
template <typename T>
__device__ void rows_body(const T* __restrict__ gcn, const T* __restrict__ wp,
                          const T* __restrict__ W, const T* __restrict__ bias,
                          float* __restrict__ Arow, float* __restrict__ Brow,
                          float* g) {
    const int row = blockIdx.x;          // b*S + s
    const int s   = row & (SS - 1);

    for (int d = threadIdx.x; d < DD; d += 256)
        g[d] = cvt(gcn[(size_t)row * DD + d]);
    __syncthreads();

    const int wave = threadIdx.x >> 6;   // 0..3
    const int lane = threadIdx.x & 63;
    const T* wpd = wp + ((size_t)row * SS + s) * EE;   // wp[b,s,s,:]

    for (int q = 0; q < 5; ++q) {
        const int t   = wave * 5 + q;     // 0..19
        const int k   = (t < KK) ? t : t - KK;
        const int off = (t < KK) ? 0 : DD;
        const T* wrow = W + (size_t)k * FF + off;

        float acc = 0.f;
        for (int d = lane; d < DD; d += 64)
            acc += g[d] * cvt(wrow[d]);
        #pragma unroll
        for (int o = 32; o > 0; o >>= 1)
            acc += __shfl_down(acc, o, 64);

        if (lane == 0) {
            const int ecol = (t < KK) ? (2 * DD) : (2 * DD + EE);  // 960 / 968
            float e = 0.f;
            #pragma unroll
            for (int ee = 0; ee < EE; ++ee)
                e += cvt(wpd[ee]) * cvt(W[(size_t)k * FF + ecol + ee]);
            const float r = acc + e;
            if (t < KK) Arow[row * KK + k] = r;
            else        Brow[row * KK + k] = r + cvt(bias[k]);
        }
    }
}

__global__ __launch_bounds__(256) void rows_kernel(
    const void* gcn, const void* wp, const void* W, const void* bias,
    const int* __restrict__ flag, float* Arow, float* Brow) {
    __shared__ float g[DD];
    if (*flag)
        rows_body<float>((const float*)gcn, (const float*)wp,
                         (const float*)W, (const float*)bias, Arow, Brow, g);
    else
        rows_body<__hip_bfloat16>((const __hip_bfloat16*)gcn, (const __hip_bfloat16*)wp,
                                  (const __hip_bfloat16*)W, (const __hip_bfloat16*)bias,
                                  Arow, Brow, g);
}

// Per-pixel: out[b,i,j,k] = Arow[b,j,k] + Brow[b,i,k]
//   + wp[b,i,j,:]·W[k,976:984]
//   + label[b,i,j,0]*W[k,984]
//   + (j>=i)*sum_{c=1..3} label[..c]*W[k,984+c]
//   + (j<=i)*sum_{c=4..9} label[..c]*W[k,984+c]
template <typename T>
__device__ void pixel_body(const T* __restrict__ label, const T* __restrict__ wp,
                           const T* __restrict__ W, const float* __restrict__ Arow,
                           const float* __restrict__ Brow, T* __restrict__ out,
                           float (*w5)[EE], float (*w6)[CC], float* brow) {
    const int bi = blockIdx.x;   // b*S + i
    const int b  = bi >> 7;
    const int i  = bi & (SS - 1);
    const int j  = threadIdx.x;  // 0..127

    for (int t = threadIdx.x; t < KK * EE + KK * CC + KK; t += 128) {
        if (t < KK * EE) {
            const int k = t / EE, e = t % EE;
            w5[k][e] = cvt(W[(size_t)k * FF + 2 * DD + 2 * EE + e]);   // col 976+e
        } else if (t < KK * EE + KK * CC) {
            const int tt = t - KK * EE;
            const int k = tt / CC, c = tt % CC;
            w6[k][c] = cvt(W[(size_t)k * FF + 2 * DD + 3 * EE + c]);   // col 984+c
        } else {
            const int k = t - KK * EE - KK * CC;
            brow[k] = Brow[bi * KK + k];
        }
    }
    __syncthreads();

    const size_t pix = (size_t)bi * SS + j;

    float wpe[EE];
    #pragma unroll
    for (int e = 0; e < EE; ++e) wpe[e] = cvt(wp[pix * EE + e]);
    float lc[CC];
    #pragma unroll
    for (int c = 0; c < CC; ++c) lc[c] = cvt(label[pix * CC + c]);

    const float mu = (j >= i) ? 1.f : 0.f;
    const float ml = (j <= i) ? 1.f : 0.f;
    #pragma unroll
    for (int c = 1; c < 4; ++c) lc[c] *= mu;
    #pragma unroll
    for (int c = 4; c < CC; ++c) lc[c] *= ml;

    const float* ap = Arow + ((size_t)b * SS + j) * KK;

    #pragma unroll
    for (int k = 0; k < KK; ++k) {
        float acc = ap[k] + brow[k];
        #pragma unroll
        for (int e = 0; e < EE; ++e) acc += wpe[e] * w5[k][e];
        #pragma unroll
        for (int c = 0; c < CC; ++c) acc += lc[c] * w6[k][c];
        stf(&out[pix * KK + k], acc);
    }
}

__global__ __launch_bounds__(128) void pixel_kernel(
    const void* label, const void* wp, const void* W,
    const float* __restrict__ Arow, const float* __restrict__ Brow,
    const int* __restrict__ flag, void* out) {
    __shared__ float w5[KK][EE];
    __shared__ float w6[KK][CC];
    __shared__ float brow[KK];
    if (*flag)
        pixel_body<float>((const float*)label, (const float*)wp, (const float*)W,
                          Arow, Brow, (float*)out, w5, w6, brow);
    else
        pixel_body<__hip_bfloat16>((const __hip_bfloat16*)label, (const __hip_bfloat16*)wp,
                                   (const __hip_bfloat16*)W, Arow, Brow,
                                   (__hip_bfloat16*)out, w5, w6, brow);
}

extern "C" void kernel_launch(void* const* d_in, const int* in_sizes, int n_in,
                              void* d_out, int out_size, void* d_ws, size_t ws_size,
                              hipStream_t stream) {
    const void* gcn   = d_in[0];  // [8,128,480]
    const void* label = d_in[1];  // [8,128,128,10]
    const void* wp    = d_in[2];  // [8,128,128,8]
    // d_in[3] = tensor_masks (all ones, unused)
    const void* W     = d_in[4];  // [10,994]
    const void* bias  = d_in[5];  // [10]

    int*   flag = (int*)d_ws;
    float* Arow = (float*)((char*)d_ws + 256);    // [B*S,K] fp32
    float* Brow = Arow + BB * SS * KK;            // [B*S,K] fp32

    detect_kernel<<<1, 64, 0, stream>>>((const unsigned short*)wp, flag);
    rows_kernel<<<BB * SS, 256, 0, stream>>>(gcn, wp, W, bias, flag, Arow, Brow);
    pixel_kernel<<<BB * SS, 128, 0, stream>>>(label, wp, W, Arow, Brow, flag, d_out);
}

// Round 5
// 82.215 us; speedup vs baseline: 1.0237x; 1.0237x over previous
//
#include <hip/hip_runtime.h>

#define BB 8
#define SS 128
#define DD 480
#define EE 8
#define CC 10
#define KK 10
#define FF 994

// All tensors are fp32 (verified round 2: the runtime-dispatch kernel took the
// fp32 branch and passed; bf16-typed reads of these buffers produce NaN).

// Kernel 1: per-(b,s) row terms (fp32 workspace).
//   Arow[b,s,k] = gcn[b,s]·W[k,0:480]   + wp[b,s,s,:]·W[k,960:968]            (j-varying part)
//   Brow[b,s,k] = gcn[b,s]·W[k,480:960] + wp[b,s,s,:]·W[k,968:976] + bias[k]  (i-varying part)
__global__ __launch_bounds__(256) void rows_kernel(
    const float* __restrict__ gcn,    // [B,S,D]
    const float* __restrict__ wp,     // [B,S,S,E]
    const float* __restrict__ W,      // [K,F]
    const float* __restrict__ bias,   // [K]
    float* __restrict__ Arow,         // [B*S,K]
    float* __restrict__ Brow)         // [B*S,K]
{
    __shared__ float g[DD];
    const int row = blockIdx.x;            // b*S + s
    const int s   = row & (SS - 1);

    // stage gcn row: 480 fp32 = 120 float4 (row base = 1920 B * row, 16B-aligned)
    const float4* g4 = reinterpret_cast<const float4*>(gcn + (size_t)row * DD);
    for (int t = threadIdx.x; t < DD / 4; t += 256) {
        const float4 v = g4[t];
        g[4 * t + 0] = v.x; g[4 * t + 1] = v.y;
        g[4 * t + 2] = v.z; g[4 * t + 3] = v.w;
    }
    __syncthreads();

    const int wave = threadIdx.x >> 6;     // 0..3
    const int lane = threadIdx.x & 63;

    for (int q = 0; q < 5; ++q) {
        const int t   = wave * 5 + q;      // 0..19: t<10 -> Arow[k=t], else Brow[k=t-10]
        const int k   = (t < KK) ? t : t - KK;
        const int off = (t < KK) ? 0 : DD;
        // W row slice base index k*994+off is even -> 8B-aligned -> float2 safe
        const float2* w2 = reinterpret_cast<const float2*>(W + (size_t)k * FF + off);

        float acc = 0.f;
        #pragma unroll
        for (int r = 0; r < 4; ++r) {
            const int idx = lane + 64 * r;             // need < 240
            if (idx < DD / 2) {
                const float2 u = w2[idx];
                acc += g[2 * idx] * u.x + g[2 * idx + 1] * u.y;
            }
        }
        #pragma unroll
        for (int o = 32; o > 0; o >>= 1)
            acc += __shfl_down(acc, o, 64);

        if (lane == 0) {
            // diag edge term: wp[b,s,s,:] · W[k, 960 or 968 : +8]
            const float* wpd = wp + ((size_t)row * SS + s) * EE;
            const float* we  = W + (size_t)k * FF + ((t < KK) ? 2 * DD : 2 * DD + EE);
            float e = 0.f;
            #pragma unroll
            for (int ee = 0; ee < EE; ++ee)
                e += wpd[ee] * we[ee];
            const float r = acc + e;
            if (t < KK) Arow[row * KK + k] = r;
            else        Brow[row * KK + k] = r + bias[k];
        }
    }
}

// Kernel 2: 256 threads = 2 i-rows of 128 pixels.
// out[b,i,j,k] = Arow[b,j,k] + Brow[b,i,k] + wp[b,i,j,:]·W[k,976:984]
//   + label[..,0]*W[k,984] + (j>=i)*sum_{c=1..3} label[..c]*W[k,984+c]
//   + (j<=i)*sum_{c=4..9} label[..c]*W[k,984+c]
__global__ __launch_bounds__(256) void pixel_kernel(
    const float* __restrict__ label,  // [B,S,S,C]
    const float* __restrict__ wp,     // [B,S,S,E]
    const float* __restrict__ W,      // [K,F]
    const float* __restrict__ Arow,   // [B*S,K]
    const float* __restrict__ Brow,   // [B*S,K]
    float* __restrict__ out)          // [B,S,S,K]
{
    const int b  = blockIdx.x >> 6;           // 8 b's x 64 blocks
    const int i0 = (blockIdx.x & 63) * 2;

    __shared__ float w5[KK][EE];              // W[:,976:984]
    __shared__ float w6[KK][CC];              // W[:,984:994]
    __shared__ float brow[2][KK];
    __shared__ float arow[SS][KK + 1];        // +1 pad: stride 11 -> <=2-way banks (free)

    {
        const int t = threadIdx.x;
        if (t < 80) {
            w5[t >> 3][t & 7] = W[(t >> 3) * FF + 2 * DD + 2 * EE + (t & 7)];     // col 976+
        } else if (t < 180) {
            const int tt = t - 80;
            w6[tt / 10][tt % 10] = W[(tt / 10) * FF + 2 * DD + 3 * EE + (tt % 10)]; // col 984+
        } else if (t < 200) {
            const int tt = t - 180;
            brow[tt / 10][tt % 10] = Brow[(b * SS + i0 + tt / 10) * KK + (tt % 10)];
        }
    }
    for (int u = threadIdx.x; u < SS * KK; u += 256)
        arow[u / KK][u % KK] = Arow[(size_t)b * SS * KK + u];
    __syncthreads();

    const int half = threadIdx.x >> 7;        // which of the 2 i-rows
    const int i    = i0 + half;
    const int j    = threadIdx.x & 127;
    const size_t pix = ((size_t)(b * SS + i)) * SS + j;

    // wp pixel: 8 fp32 = 32 B, 32B-aligned -> 2x float4
    float wpe[EE];
    {
        const float4* p4 = reinterpret_cast<const float4*>(wp + pix * EE);
        const float4 a = p4[0], c = p4[1];
        wpe[0] = a.x; wpe[1] = a.y; wpe[2] = a.z; wpe[3] = a.w;
        wpe[4] = c.x; wpe[5] = c.y; wpe[6] = c.z; wpe[7] = c.w;
    }
    // label pixel: 10 fp32 = 40 B, 8B-aligned -> 5x float2
    float lc[CC];
    {
        const float2* p2 = reinterpret_cast<const float2*>(label + pix * CC);
        #pragma unroll
        for (int p = 0; p < 5; ++p) {
            const float2 v = p2[p];
            lc[2 * p] = v.x; lc[2 * p + 1] = v.y;
        }
    }

    const float mu = (j >= i) ? 1.f : 0.f;    // upper-tri, channels 1..3
    const float ml = (j <= i) ? 1.f : 0.f;    // lower-tri, channels 4..9
    #pragma unroll
    for (int c = 1; c < 4; ++c) lc[c] *= mu;
    #pragma unroll
    for (int c = 4; c < CC; ++c) lc[c] *= ml;

    float o[KK];
    #pragma unroll
    for (int k = 0; k < KK; ++k) {
        float acc = arow[j][k] + brow[half][k];
        #pragma unroll
        for (int e = 0; e < EE; ++e) acc += wpe[e] * w5[k][e];
        #pragma unroll
        for (int c = 0; c < CC; ++c) acc += lc[c] * w6[k][c];
        o[k] = acc;
    }

    float2* op = reinterpret_cast<float2*>(out + pix * KK);
    #pragma unroll
    for (int p = 0; p < 5; ++p)
        op[p] = make_float2(o[2 * p], o[2 * p + 1]);
}

extern "C" void kernel_launch(void* const* d_in, const int* in_sizes, int n_in,
                              void* d_out, int out_size, void* d_ws, size_t ws_size,
                              hipStream_t stream) {
    const float* gcn   = (const float*)d_in[0];  // [8,128,480]
    const float* label = (const float*)d_in[1];  // [8,128,128,10]
    const float* wp    = (const float*)d_in[2];  // [8,128,128,8]
    // d_in[3] = tensor_masks (all ones, unused by the math)
    const float* W     = (const float*)d_in[4];  // [10,994]
    const float* bias  = (const float*)d_in[5];  // [10]
    float* out = (float*)d_out;                  // [8,128,128,10]

    float* Arow = (float*)d_ws;                  // [1024,10] fp32
    float* Brow = Arow + BB * SS * KK;           // [1024,10] fp32

    rows_kernel<<<BB * SS, 256, 0, stream>>>(gcn, wp, W, bias, Arow, Brow);
    pixel_kernel<<<BB * SS / 2, 256, 0, stream>>>(label, wp, W, Arow, Brow, out);
}